// Round 15
// baseline (1429.247 us; speedup 1.0000x reference)
//
#include <hip/hip_runtime.h>
#include <hip/hip_bf16.h>

#define NTOK 8192
#define DIM 1024
#define NEXP 8
#define NT 256   // virtual K tiles: 16 segments (expert x half) x 16 tiles of BK=64
#define BK 64
#define NELEMZ ((size_t)NTOK * DIM)

typedef float f32x4 __attribute__((ext_vector_type(4)));
typedef short s16x8 __attribute__((ext_vector_type(8)));
typedef unsigned short u16;
typedef unsigned short u16x4 __attribute__((ext_vector_type(4)));

__device__ __forceinline__ u16 f2bf(float f) {
    __hip_bfloat16 h = __float2bfloat16(f);
    return *reinterpret_cast<u16*>(&h);
}

#define GLOAD16(gsrc, ldst)                                                     \
    __builtin_amdgcn_global_load_lds(                                           \
        (const __attribute__((address_space(1))) void*)(gsrc),                  \
        (__attribute__((address_space(3))) void*)(ldst), 16, 0, 0)

#define MFMA16(a, b, c) __builtin_amdgcn_mfma_f32_16x16x32_bf16((a), (b), (c), 0, 0, 0)

// ---------------- gates: softmax -> TRANSPOSED gT[e][n] ----------------
__global__ __launch_bounds__(256) void gates_kernel(
    const float* __restrict__ zr, const float* __restrict__ zi,
    const float* __restrict__ Wg, const float* __restrict__ bg,
    float* __restrict__ gT)
{
    const int wave = threadIdx.x >> 6, lane = threadIdx.x & 63;
    const int n = blockIdx.x * 4 + wave;

    float v[32];
    const float* zrp = zr + (size_t)n * DIM;
    const float* zip = zi + (size_t)n * DIM;
#pragma unroll
    for (int j = 0; j < 16; ++j) v[j] = zrp[j * 64 + lane];
#pragma unroll
    for (int j = 0; j < 16; ++j) v[16 + j] = zip[j * 64 + lane];

    float s[NEXP];
#pragma unroll
    for (int e = 0; e < NEXP; ++e) {
        const float* wrow = Wg + (size_t)e * (2 * DIM);
        float a = 0.f;
#pragma unroll
        for (int j = 0; j < 32; ++j) a += v[j] * wrow[j * 64 + lane];
#pragma unroll
        for (int m = 32; m; m >>= 1) a += __shfl_xor(a, m);
        s[e] = a + bg[e];
    }
    float mx = s[0];
#pragma unroll
    for (int e = 1; e < NEXP; ++e) mx = fmaxf(mx, s[e]);
    float p[NEXP], sum = 0.f;
#pragma unroll
    for (int e = 0; e < NEXP; ++e) { p[e] = expf(s[e] - mx); sum += p[e]; }
    const float inv = 1.f / sum;
    if (lane == 0) {
#pragma unroll
        for (int e = 0; e < NEXP; ++e) gT[(size_t)e * NTOK + n] = p[e] * inv;
    }
}

// ---------------- fp32 -> bf16 conversion (z and W) ----------------
__global__ __launch_bounds__(256) void cvt4_kernel(
    const float* __restrict__ zr, const float* __restrict__ zi,
    const float* __restrict__ Wr, const float* __restrict__ Wi,
    u16* __restrict__ zr16, u16* __restrict__ zi16,
    u16* __restrict__ Wr16, u16* __restrict__ Wi16)
{
    const size_t total = NELEMZ / 4;
    for (size_t i = (size_t)blockIdx.x * 256 + threadIdx.x; i < total;
         i += (size_t)gridDim.x * 256) {
        f32x4 a = ((const f32x4*)zr)[i];
        f32x4 b = ((const f32x4*)zi)[i];
        f32x4 c = ((const f32x4*)Wr)[i];
        f32x4 d = ((const f32x4*)Wi)[i];
        u16x4 pa, pb, pc, pd;
#pragma unroll
        for (int j = 0; j < 4; ++j) {
            pa[j] = f2bf(a[j]); pb[j] = f2bf(b[j]);
            pc[j] = f2bf(c[j]); pd[j] = f2bf(d[j]);
        }
        ((u16x4*)zr16)[i] = pa;
        ((u16x4*)zi16)[i] = pb;
        ((u16x4*)Wr16)[i] = pc;
        ((u16x4*)Wi16)[i] = pd;
    }
}

// ---------------- main MoE GEMM: A-in-regs, segment-epilogue gating ----------
// 512 blocks x 512 threads = 8 waves (2M x 4N), per-wave 64x64:
// acc[4][4] + tot[4][4]. Tile 128x256, BK=64, virtual K = 16 seg x 1024.
// A: UNSCALED bf16 fragments loaded straight from global (row-major z16 maps
//    exactly onto the MFMA A-frag pattern; 16 rows x 64B per wave-instr;
//    4x wc-duplication absorbed by L1). Zero LDS, zero VALU for A.
// B: LDS double-buffer (r8-proven swizzle staging), 8 ds_reads/wave/tile.
// Gate: per-segment epilogue tot += sg*acc (r2-proven numerics); sign folded.
// One barrier per tile; vmcnt(0)+lgkm(0) tail (nothing useful left in flight:
// A-consumption already retired the B(t+1) gloads via FIFO).
// LDS 64 KB -> 2 blocks/CU -> 4 waves/SIMD TLP does the DS/MFMA overlap.
__global__ __launch_bounds__(512, 2) void moe_gemm15(
    const u16* __restrict__ zr16, const u16* __restrict__ zi16,
    const u16* __restrict__ Wr16, const u16* __restrict__ Wi16,
    const float* __restrict__ gT, float* __restrict__ out)
{
    extern __shared__ u16 lds[];  // B: 2 slots x 16384 elems (32 KB each)

    // XCD map: xcd = bid&7 owns bm range [xcd*8, xcd*8+8) x all 8 (bn,sel);
    // A-slice (2 MB z16) and B e-window stay L2-resident per XCD.
    const int bid = blockIdx.x;
    const int xcd = bid & 7;
    const int loc = bid >> 3;            // 0..63
    const int grp = loc & 7;
    const int bm = xcd * 8 + (loc >> 3); // 0..63
    const int bn = grp & 3, sel = grp >> 2;

    const int tid = threadIdx.x;
    const int lane = tid & 63;
    const int wid = tid >> 6;
    const int wr = wid >> 2;   // 0..1
    const int wc = wid & 3;    // 0..3

    // ---- B staging addressing (r8 verbatim; swizzle c ^= row&7 on source) ----
    const int srow = tid >> 3;
    const int schunk = (tid & 7) ^ (srow & 7);
    int brow[4];
#pragma unroll
    for (int j = 0; j < 4; ++j)
        brow[j] = (bn * 256 + srow + j * 64) * DIM + schunk * 8;

    // ---- B fragment read addressing (elems; r8 verbatim) ----
    const int cg = lane >> 4;
    const int l7 = lane & 7;
    const int ach0 = (cg ^ l7) * 8;
    const int ach1 = ((4 + cg) ^ l7) * 8;
    const int brbase = (wc * 64 + (lane & 15)) * BK;

    // ---- A fragment GLOBAL addressing: row (lane&15)+m*16, k kg*8+ks*32 ----
    const int arowb = (bm * 128 + wr * 64 + (lane & 15)) * DIM + (lane >> 4) * 8;

    const int grow0 = bm * 128 + wr * 64 + ((lane >> 4) << 2);

    f32x4 acc[4][4], tot[4][4];
#pragma unroll
    for (int m = 0; m < 4; ++m)
#pragma unroll
        for (int n = 0; n < 4; ++n) {
            acc[m][n] = (f32x4){0.f, 0.f, 0.f, 0.f};
            tot[m][n] = (f32x4){0.f, 0.f, 0.f, 0.f};
        }

    const u16* Asrc = sel ? zi16 : zr16;   // seg 0
    const u16* Bseg1 = Wr16;               // B source for staged tile (t+1)
    f32x4 sgm[4];

    // ---- prologue: stage B(0) into slot 0 ----
#pragma unroll
    for (int q = 0; q < 4; ++q)
        GLOAD16(Wr16 + brow[q], &lds[(q * 512 + tid) * 8]);
    asm volatile("s_waitcnt vmcnt(0)" ::: "memory");
    __builtin_amdgcn_s_barrier();

#pragma unroll 1
    for (int t = 0; t < NT; ++t) {
        if ((t & 15) == 0) {  // segment boundary: finalize prev, load gates
            const int seg = t >> 4;
            if (t) {
#pragma unroll
                for (int m = 0; m < 4; ++m)
#pragma unroll
                    for (int n = 0; n < 4; ++n) {
#pragma unroll
                        for (int j = 0; j < 4; ++j)
                            tot[m][n][j] += sgm[m][j] * acc[m][n][j];
                        acc[m][n] = (f32x4){0.f, 0.f, 0.f, 0.f};
                    }
            }
            const int e = seg >> 1, half = seg & 1;
            Asrc = (half ^ sel) ? zi16 : zr16;
            const float sgn = (sel == 0 && half == 1) ? -1.f : 1.f;
#pragma unroll
            for (int m = 0; m < 4; ++m) {
                const f32x4 g = *(const f32x4*)&gT[(size_t)e * NTOK + grow0 + m * 16];
#pragma unroll
                for (int j = 0; j < 4; ++j) sgm[m][j] = sgn * g[j];
            }
        }
        const int t1 = t + 1;
        if ((t1 & 15) == 0) {  // B source for tile t+1 (t1=256 dead-wraps to Wr)
            const int seg = t1 >> 4;
            const int e = (seg >> 1) & 7;
            Bseg1 = ((seg & 1) ? Wi16 : Wr16) + (size_t)e * DIM * DIM;
        }
        const int kb = (t & 15) << 6;        // A k base (current tile)
        const int kb1 = (t1 & 15) << 6;      // B staging k base
        const int rs = t & 1;
        const int bb = rs * 16384 + brbase;  // B read base
        const int sb = (rs ^ 1) * 16384;     // B staging dest

        // ---- stage B(t+1) (4 gloads), then A(t) fragment loads (8 b128) ----
        GLOAD16(Bseg1 + brow[0] + kb1, &lds[sb + (0 * 512 + tid) * 8]);
        GLOAD16(Bseg1 + brow[1] + kb1, &lds[sb + (1 * 512 + tid) * 8]);
        GLOAD16(Bseg1 + brow[2] + kb1, &lds[sb + (2 * 512 + tid) * 8]);
        GLOAD16(Bseg1 + brow[3] + kb1, &lds[sb + (3 * 512 + tid) * 8]);
        s16x8 a[8];
#pragma unroll
        for (int ks = 0; ks < 2; ++ks)
#pragma unroll
            for (int m = 0; m < 4; ++m)
                a[ks * 4 + m] = *(const s16x8*)(Asrc + arowb + m * 16 * DIM + ks * 32 + kb);

        // ---- ks0: 4 ds_reads + 16 MFMA ----
        s16x8 b0[4];
#pragma unroll
        for (int n = 0; n < 4; ++n) b0[n] = *(const s16x8*)&lds[bb + n * 1024 + ach0];
        __builtin_amdgcn_s_setprio(1);
#pragma unroll
        for (int m = 0; m < 4; ++m)
#pragma unroll
            for (int n = 0; n < 4; ++n) acc[m][n] = MFMA16(a[m], b0[n], acc[m][n]);
        __builtin_amdgcn_s_setprio(0);

        // ---- ks1: 4 ds_reads + 16 MFMA ----
        s16x8 b1[4];
#pragma unroll
        for (int n = 0; n < 4; ++n) b1[n] = *(const s16x8*)&lds[bb + n * 1024 + ach1];
        __builtin_amdgcn_s_setprio(1);
#pragma unroll
        for (int m = 0; m < 4; ++m)
#pragma unroll
            for (int n = 0; n < 4; ++n) acc[m][n] = MFMA16(a[4 + m], b1[n], acc[m][n]);
        __builtin_amdgcn_s_setprio(0);

        // ---- tile end: B(t+1) already retired via FIFO (A consumed after);
        //      lgkm(0) orders this tile's ds_reads before next staging ----
        asm volatile("s_waitcnt vmcnt(0) lgkmcnt(0)" ::: "memory");
        __builtin_amdgcn_s_barrier();
    }

    // ---- finalize last segment ----
#pragma unroll
    for (int m = 0; m < 4; ++m)
#pragma unroll
        for (int n = 0; n < 4; ++n)
#pragma unroll
            for (int j = 0; j < 4; ++j)
                tot[m][n][j] += sgm[m][j] * acc[m][n][j];

    // ---- epilogue: C[row][col], col=lane&15, row=(lane>>4)*4+j (m89) ----
    float* op = out + (size_t)sel * NTOK * DIM;
    const int col0 = bn * 256 + wc * 64 + (lane & 15);
#pragma unroll
    for (int m = 0; m < 4; ++m)
#pragma unroll
        for (int n = 0; n < 4; ++n)
#pragma unroll
            for (int j = 0; j < 4; ++j)
                op[(size_t)(grow0 + m * 16 + j) * DIM + col0 + n * 16] = tot[m][n][j];
}

extern "C" void kernel_launch(void* const* d_in, const int* in_sizes, int n_in,
                              void* d_out, int out_size, void* d_ws, size_t ws_size,
                              hipStream_t stream) {
    const float* zr = (const float*)d_in[0];
    const float* zi = (const float*)d_in[1];
    const float* Wg = (const float*)d_in[2];
    const float* bg = (const float*)d_in[3];
    const float* Wr = (const float*)d_in[4];
    const float* Wi = (const float*)d_in[5];
    float* out = (float*)d_out;

    u16* zr16 = (u16*)d_ws;
    u16* zi16 = zr16 + NELEMZ;
    u16* Wr16 = zi16 + NELEMZ;
    u16* Wi16 = Wr16 + NELEMZ;
    float* gT = (float*)(Wi16 + NELEMZ);   // [NEXP][NTOK]

    cvt4_kernel<<<2048, 256, 0, stream>>>(zr, zi, Wr, Wi, zr16, zi16, Wr16, Wi16);
    gates_kernel<<<NTOK / 4, 256, 0, stream>>>(zr, zi, Wg, bg, gT);

    hipFuncSetAttribute((const void*)moe_gemm15,
                        hipFuncAttributeMaxDynamicSharedMemorySize, 65536);
    moe_gemm15<<<512, 512, 65536, stream>>>(zr16, zi16, Wr16, Wi16, gT, out);
}

// Round 16
// 580.352 us; speedup vs baseline: 2.4627x; 2.4627x over previous
//
#include <hip/hip_runtime.h>
#include <hip/hip_bf16.h>

#define NTOK 8192
#define DIM 1024
#define NEXP 8
#define NT 256   // virtual K tiles: 16 segments (expert x half) x 16 tiles of BK=64
#define BK 64
#define NELEMZ ((size_t)NTOK * DIM)

typedef float f32x4 __attribute__((ext_vector_type(4)));
typedef short s16x8 __attribute__((ext_vector_type(8)));
typedef unsigned short u16;
typedef unsigned short u16x4 __attribute__((ext_vector_type(4)));

__device__ __forceinline__ u16 f2bf(float f) {
    __hip_bfloat16 h = __float2bfloat16(f);
    return *reinterpret_cast<u16*>(&h);
}

#define GLOAD16(gsrc, ldst)                                                     \
    __builtin_amdgcn_global_load_lds(                                           \
        (const __attribute__((address_space(1))) void*)(gsrc),                  \
        (__attribute__((address_space(3))) void*)(ldst), 16, 0, 0)

#define MFMA16(a, b, c) __builtin_amdgcn_mfma_f32_16x16x32_bf16((a), (b), (c), 0, 0, 0)

// ---------------- gates: softmax -> TRANSPOSED gT[e][n] ----------------
__global__ __launch_bounds__(256) void gates_kernel(
    const float* __restrict__ zr, const float* __restrict__ zi,
    const float* __restrict__ Wg, const float* __restrict__ bg,
    float* __restrict__ gT)
{
    const int wave = threadIdx.x >> 6, lane = threadIdx.x & 63;
    const int n = blockIdx.x * 4 + wave;

    float v[32];
    const float* zrp = zr + (size_t)n * DIM;
    const float* zip = zi + (size_t)n * DIM;
#pragma unroll
    for (int j = 0; j < 16; ++j) v[j] = zrp[j * 64 + lane];
#pragma unroll
    for (int j = 0; j < 16; ++j) v[16 + j] = zip[j * 64 + lane];

    float s[NEXP];
#pragma unroll
    for (int e = 0; e < NEXP; ++e) {
        const float* wrow = Wg + (size_t)e * (2 * DIM);
        float a = 0.f;
#pragma unroll
        for (int j = 0; j < 32; ++j) a += v[j] * wrow[j * 64 + lane];
#pragma unroll
        for (int m = 32; m; m >>= 1) a += __shfl_xor(a, m);
        s[e] = a + bg[e];
    }
    float mx = s[0];
#pragma unroll
    for (int e = 1; e < NEXP; ++e) mx = fmaxf(mx, s[e]);
    float p[NEXP], sum = 0.f;
#pragma unroll
    for (int e = 0; e < NEXP; ++e) { p[e] = expf(s[e] - mx); sum += p[e]; }
    const float inv = 1.f / sum;
    if (lane == 0) {
#pragma unroll
        for (int e = 0; e < NEXP; ++e) gT[(size_t)e * NTOK + n] = p[e] * inv;
    }
}

// ---------------- fp32 -> bf16 conversion (z and W) ----------------
__global__ __launch_bounds__(256) void cvt4_kernel(
    const float* __restrict__ zr, const float* __restrict__ zi,
    const float* __restrict__ Wr, const float* __restrict__ Wi,
    u16* __restrict__ zr16, u16* __restrict__ zi16,
    u16* __restrict__ Wr16, u16* __restrict__ Wi16)
{
    const size_t total = NELEMZ / 4;
    for (size_t i = (size_t)blockIdx.x * 256 + threadIdx.x; i < total;
         i += (size_t)gridDim.x * 256) {
        f32x4 a = ((const f32x4*)zr)[i];
        f32x4 b = ((const f32x4*)zi)[i];
        f32x4 c = ((const f32x4*)Wr)[i];
        f32x4 d = ((const f32x4*)Wi)[i];
        u16x4 pa, pb, pc, pd;
#pragma unroll
        for (int j = 0; j < 4; ++j) {
            pa[j] = f2bf(a[j]); pb[j] = f2bf(b[j]);
            pc[j] = f2bf(c[j]); pd[j] = f2bf(d[j]);
        }
        ((u16x4*)zr16)[i] = pa;
        ((u16x4*)zi16)[i] = pb;
        ((u16x4*)Wr16)[i] = pc;
        ((u16x4*)Wi16)[i] = pd;
    }
}

// ---------------- main MoE GEMM: 128x128 tile, 2 independent blocks/CU -------
// 1024 blocks x 256 threads = 4 waves (2M x 2N), per-wave 64x64:
// acc[4][4]+tot[4][4] = 128 VGPR. BK=64, virtual K = 16 seg x 1024.
// ZERO in-loop VALU: A staged UNSCALED via global_load_lds (z16), gate applied
// in the segment epilogue (tot += sg*acc, r15-proven numerics). A+B both
// double-buffered in 64 KB LDS -> 2 blocks/CU with INDEPENDENT barriers:
// when one block sits in its tile-end drain, the other issues MFMA
// (cross-block pipe overlap -- the desync r8's single 8-wave block cannot do).
// Swizzle (chunk c ^= row&7, inverse on source) = r8-proven, conflict-free.
__global__ __launch_bounds__(256, 2) void moe_gemm16(
    const u16* __restrict__ zr16, const u16* __restrict__ zi16,
    const u16* __restrict__ Wr16, const u16* __restrict__ Wi16,
    const float* __restrict__ gT, float* __restrict__ out)
{
    extern __shared__ u16 lds[];  // elems: A slot s: s*8192; B: 16384 + s*8192

    // XCD map: xcd = bid&7 owns bm range [xcd*8, xcd*8+8) x all 16 (bn,sel);
    // per-XCD A-slice (2 MB) and per-segment B window (2 MB) stay L2-resident.
    const int bid = blockIdx.x;            // 0..1023
    const int xcd = bid & 7;
    const int loc = bid >> 3;              // 0..127
    const int bm = xcd * 8 + (loc >> 4);   // 0..63
    const int grp = loc & 15;
    const int bn = grp & 7;                // 0..7
    const int sel = grp >> 3;

    const int tid = threadIdx.x;
    const int lane = tid & 63;
    const int wid = tid >> 6;
    const int wr = wid >> 1;   // 0..1
    const int wc = wid & 1;    // 0..1

    // ---- staging addressing: 4 gload instrs each for A and B (16 KB each);
    //      instr q covers linear chunks q*256+tid; inverse swizzle on source ----
    int ar_g[4], br_g[4];
#pragma unroll
    for (int q = 0; q < 4; ++q) {
        const int idx = q * 256 + tid;     // 0..1023
        const int row = idx >> 3;          // 0..127
        const int c = (idx & 7) ^ (row & 7);
        ar_g[q] = (bm * 128 + row) * DIM + c * 8;
        br_g[q] = (bn * 128 + row) * DIM + c * 8;
    }

    // ---- fragment read addressing (elems; r8 formulas) ----
    const int cg = lane >> 4;
    const int l7 = lane & 7;
    const int ach0 = (cg ^ l7) * 8;
    const int ach1 = ((4 + cg) ^ l7) * 8;
    const int abase = (wr * 64 + (lane & 15)) * BK;   // + m*1024 + ach
    const int bbase = (wc * 64 + (lane & 15)) * BK;   // + n*1024 + ach

    const int grow0 = bm * 128 + wr * 64 + ((lane >> 4) << 2);

    f32x4 acc[4][4], tot[4][4];
#pragma unroll
    for (int m = 0; m < 4; ++m)
#pragma unroll
        for (int n = 0; n < 4; ++n) {
            acc[m][n] = (f32x4){0.f, 0.f, 0.f, 0.f};
            tot[m][n] = (f32x4){0.f, 0.f, 0.f, 0.f};
        }

    // ---- segment state (sources track the tile being STAGED = t+1) ----
    const u16* Asrc = sel ? zi16 : zr16;   // seg 0
    const u16* Bseg = Wr16;                // seg 0
    f32x4 sgm[4];

    // ---- prologue: stage A(0),B(0) into slot 0 ----
#pragma unroll
    for (int q = 0; q < 4; ++q) GLOAD16(Asrc + ar_g[q], &lds[(q * 256 + tid) * 8]);
#pragma unroll
    for (int q = 0; q < 4; ++q) GLOAD16(Bseg + br_g[q], &lds[16384 + (q * 256 + tid) * 8]);
    asm volatile("s_waitcnt vmcnt(0)" ::: "memory");
    __builtin_amdgcn_s_barrier();

#pragma unroll 1
    for (int t = 0; t < NT; ++t) {
        if ((t & 15) == 0) {  // segment boundary: fold previous, load gates
            const int seg = t >> 4;
            if (t) {
#pragma unroll
                for (int m = 0; m < 4; ++m)
#pragma unroll
                    for (int n = 0; n < 4; ++n) {
#pragma unroll
                        for (int j = 0; j < 4; ++j)
                            tot[m][n][j] += sgm[m][j] * acc[m][n][j];
                        acc[m][n] = (f32x4){0.f, 0.f, 0.f, 0.f};
                    }
            }
            const int e = seg >> 1, half = seg & 1;
            const float sgn = (sel == 0 && half == 1) ? -1.f : 1.f;
#pragma unroll
            for (int m = 0; m < 4; ++m) {
                const f32x4 g = *(const f32x4*)&gT[(size_t)e * NTOK + grow0 + m * 16];
#pragma unroll
                for (int j = 0; j < 4; ++j) sgm[m][j] = sgn * g[j];
            }
        }
        const int t1 = t + 1;
        if ((t1 & 15) == 0) {  // staging sources for tile t+1 (t1=256 dead-wraps)
            const int seg = t1 >> 4;
            const int e = (seg >> 1) & 7;
            const int half = seg & 1;
            Asrc = (half ^ sel) ? zi16 : zr16;
            Bseg = (half ? Wi16 : Wr16) + (size_t)e * DIM * DIM;
        }
        const int kb = (t1 & 15) << 6;        // staging k base (elems)
        const int rs = t & 1;
        const int sa = (rs ^ 1) * 8192;       // A staging dest (elems)
        const int sb = 16384 + (rs ^ 1) * 8192;
        const int ab = rs * 8192 + abase;     // A read base
        const int bb = 16384 + rs * 8192 + bbase;

        // ---- stage t+1: 8 gloads (A then B), full-tile latency cover ----
        GLOAD16(Asrc + ar_g[0] + kb, &lds[sa + (0 * 256 + tid) * 8]);
        GLOAD16(Asrc + ar_g[1] + kb, &lds[sa + (1 * 256 + tid) * 8]);
        GLOAD16(Asrc + ar_g[2] + kb, &lds[sa + (2 * 256 + tid) * 8]);
        GLOAD16(Asrc + ar_g[3] + kb, &lds[sa + (3 * 256 + tid) * 8]);
        GLOAD16(Bseg + br_g[0] + kb, &lds[sb + (0 * 256 + tid) * 8]);
        GLOAD16(Bseg + br_g[1] + kb, &lds[sb + (1 * 256 + tid) * 8]);
        GLOAD16(Bseg + br_g[2] + kb, &lds[sb + (2 * 256 + tid) * 8]);
        GLOAD16(Bseg + br_g[3] + kb, &lds[sb + (3 * 256 + tid) * 8]);

        // ---- ks0: 8 ds_reads + 16 MFMA ----
        s16x8 a0[4], b0[4];
#pragma unroll
        for (int m = 0; m < 4; ++m) a0[m] = *(const s16x8*)&lds[ab + m * 1024 + ach0];
#pragma unroll
        for (int n = 0; n < 4; ++n) b0[n] = *(const s16x8*)&lds[bb + n * 1024 + ach0];
        __builtin_amdgcn_s_setprio(1);
#pragma unroll
        for (int m = 0; m < 4; ++m)
#pragma unroll
            for (int n = 0; n < 4; ++n) acc[m][n] = MFMA16(a0[m], b0[n], acc[m][n]);
        __builtin_amdgcn_s_setprio(0);

        // ---- ks1: 8 ds_reads + 16 MFMA ----
        s16x8 a1[4], b1[4];
#pragma unroll
        for (int m = 0; m < 4; ++m) a1[m] = *(const s16x8*)&lds[ab + m * 1024 + ach1];
#pragma unroll
        for (int n = 0; n < 4; ++n) b1[n] = *(const s16x8*)&lds[bb + n * 1024 + ach1];
        __builtin_amdgcn_s_setprio(1);
#pragma unroll
        for (int m = 0; m < 4; ++m)
#pragma unroll
            for (int n = 0; n < 4; ++n) acc[m][n] = MFMA16(a1[m], b1[n], acc[m][n]);
        __builtin_amdgcn_s_setprio(0);

        // ---- tile end: slot rs^1 fully staged + this tile's reads retired ----
        asm volatile("s_waitcnt vmcnt(0) lgkmcnt(0)" ::: "memory");
        __builtin_amdgcn_s_barrier();
    }

    // ---- finalize last segment ----
#pragma unroll
    for (int m = 0; m < 4; ++m)
#pragma unroll
        for (int n = 0; n < 4; ++n)
#pragma unroll
            for (int j = 0; j < 4; ++j)
                tot[m][n][j] += sgm[m][j] * acc[m][n][j];

    // ---- epilogue: C[row][col], col=lane&15, row=(lane>>4)*4+j (m89) ----
    float* op = out + (size_t)sel * NTOK * DIM;
    const int col0 = bn * 128 + wc * 64 + (lane & 15);
#pragma unroll
    for (int m = 0; m < 4; ++m)
#pragma unroll
        for (int n = 0; n < 4; ++n)
#pragma unroll
            for (int j = 0; j < 4; ++j)
                op[(size_t)(grow0 + m * 16 + j) * DIM + col0 + n * 16] = tot[m][n][j];
}

extern "C" void kernel_launch(void* const* d_in, const int* in_sizes, int n_in,
                              void* d_out, int out_size, void* d_ws, size_t ws_size,
                              hipStream_t stream) {
    const float* zr = (const float*)d_in[0];
    const float* zi = (const float*)d_in[1];
    const float* Wg = (const float*)d_in[2];
    const float* bg = (const float*)d_in[3];
    const float* Wr = (const float*)d_in[4];
    const float* Wi = (const float*)d_in[5];
    float* out = (float*)d_out;

    u16* zr16 = (u16*)d_ws;
    u16* zi16 = zr16 + NELEMZ;
    u16* Wr16 = zi16 + NELEMZ;
    u16* Wi16 = Wr16 + NELEMZ;
    float* gT = (float*)(Wi16 + NELEMZ);   // [NEXP][NTOK]

    cvt4_kernel<<<2048, 256, 0, stream>>>(zr, zi, Wr, Wi, zr16, zi16, Wr16, Wi16);
    gates_kernel<<<NTOK / 4, 256, 0, stream>>>(zr, zi, Wg, bg, gT);

    hipFuncSetAttribute((const void*)moe_gemm16,
                        hipFuncAttributeMaxDynamicSharedMemorySize, 65536);
    moe_gemm16<<<1024, 256, 65536, stream>>>(zr16, zi16, Wr16, Wi16, gT, out);
}